// Round 3
// baseline (347.259 us; speedup 1.0000x reference)
//
#include <hip/hip_runtime.h>

#define BB 4
#define CIN 32
#define COUT 32
#define TT 48
#define NN 2000
#define EE 16000
#define BT (BB*TT)
#define PADCOL 24576   // padded CSR capacity (16000 + 2000*3 = 22000 max)

// ---- fused build: CSR (padded rows) + degree terms + weight prep --------
// Single block, 1024 threads. LDS atomics for count, LDS scan, LDS fill
// counters. Also: w1t = transpose(w1) -> [3][ci][c]; w2c[k] = gcn_w @ w2[k];
// bias2[k] = gcn_b @ w2[k].

__global__ __launch_bounds__(1024) void k_build(
        const int* __restrict__ ei,
        const float* __restrict__ w1, const float* __restrict__ gw,
        const float* __restrict__ gb, const float* __restrict__ w2,
        int* __restrict__ rowptr, float* __restrict__ dinv2,
        int* __restrict__ col, float* __restrict__ wedge,
        float* __restrict__ w1t, float* __restrict__ w2c,
        float* __restrict__ bias2) {
    __shared__ int   cnt[2048];
    __shared__ int   buf[2048];
    __shared__ float sdinv[2048];
    int t = threadIdx.x;

    // 1. zero counters
    cnt[t] = 0; cnt[t + 1024] = 0;
    __syncthreads();

    // 2. count in-degrees (LDS atomics)
    for (int e = t; e < EE; e += 1024) atomicAdd(&cnt[ei[EE + e]], 1);
    __syncthreads();

    // 3. inclusive scan over PADDED counts (pad each row to multiple of 4)
    for (int i = t; i < 2048; i += 1024)
        buf[i] = (i < NN) ? ((cnt[i] + 3) & ~3) : 0;
    __syncthreads();
    for (int s = 1; s < 2048; s <<= 1) {
        int i0 = t, i1 = t + 1024;
        int a0 = buf[i0] + ((i0 >= s) ? buf[i0 - s] : 0);
        int a1 = buf[i1] + ((i1 >= s) ? buf[i1 - s] : 0);
        __syncthreads();
        buf[i0] = a0; buf[i1] = a1;
        __syncthreads();
    }

    // 4. rowptr + degree terms (deg = 1 + in-degree)
    for (int i = t; i < 2048; i += 1024) {
        if (i < NN) {
            rowptr[i + 1] = buf[i];
            float deg = (float)(cnt[i] + 1);
            sdinv[i] = rsqrtf(deg);
            dinv2[i] = 1.0f / deg;
        }
    }
    if (t == 0) rowptr[0] = 0;
    __syncthreads();

    // 5. zero padded col/wedge, then repoint cnt[] to row starts
    int P = buf[NN - 1];
    for (int i = t; i < P; i += 1024) { col[i] = 0; wedge[i] = 0.f; }
    for (int i = t; i < NN; i += 1024)
        cnt[i] = buf[i] - ((cnt[i] + 3) & ~3);   // exclusive (padded) start
    __syncthreads();

    // 6. fill real edges
    for (int e = t; e < EE; e += 1024) {
        int s = ei[e], d = ei[EE + e];
        int pos = atomicAdd(&cnt[d], 1);
        col[pos]   = s;
        wedge[pos] = sdinv[s] * sdinv[d];
    }

    // 7. weight prep (no LDS dependency)
    // w1t[(k*32+ci)*32+c] = w1[c*96+ci*3+k]
    for (int i = t; i < 3072; i += 1024) {
        int c = i & 31, ci = (i >> 5) & 31, k = i >> 10;
        w1t[i] = w1[c * 96 + ci * 3 + k];
        // w2c[(k*32+cm)*32+c] = sum_co gw[cm*32+co] * w2[c*96+co*3+k]
        int cm = ci;
        float acc = 0.f;
        for (int co = 0; co < 32; co++)
            acc += gw[cm * 32 + co] * w2[c * 96 + co * 3 + k];
        w2c[i] = acc;
    }
    // bias2[k*32+c] = sum_co gb[co] * w2[c*96+co*3+k]
    for (int i = t; i < 96; i += 1024) {
        int k = i >> 5, c = i & 31;
        float acc = 0.f;
        for (int co = 0; co < 32; co++)
            acc += gb[co] * w2[c * 96 + co * 3 + k];
        bias2[i] = acc;
    }
}

// ---- conv1: temporal conv + relu -> h [BT, N, 32] (c fastest) -----------
// 2 nodes/thread, float2 x loads, scalar-uniform weight reads.

__global__ __launch_bounds__(256) void k_conv1(const float* __restrict__ x,
                                               const float* __restrict__ w1t,
                                               const float* __restrict__ b1,
                                               float* __restrict__ hbuf) {
    int idx = blockIdx.x * 256 + threadIdx.x;   // node-pair index
    int n0 = idx * 2;
    if (n0 >= NN) return;
    int t = blockIdx.y, b = blockIdx.z;

    float ha[COUT], hb[COUT];
#pragma unroll
    for (int c = 0; c < COUT; c++) { ha[c] = b1[c]; hb[c] = b1[c]; }

    for (int k = 0; k < 3; k++) {
        int tt = t + k - 1;
        if (tt < 0 || tt >= TT) continue;
        const float* xb = x + (((size_t)b * CIN) * TT + tt) * NN + n0;
        const float* wp = w1t + k * CIN * COUT;
#pragma unroll
        for (int ci = 0; ci < CIN; ci++) {
            float2 xv = *(const float2*)(xb + (size_t)ci * TT * NN);
#pragma unroll
            for (int c = 0; c < COUT; c++) {
                float wv = wp[ci * COUT + c];
                ha[c] += xv.x * wv;
                hb[c] += xv.y * wv;
            }
        }
    }

    float4* pa = (float4*)(hbuf + (((size_t)(b * TT + t)) * NN + n0) * COUT);
    float4* pb = pa + 8;
#pragma unroll
    for (int q = 0; q < 8; q++) {
        pa[q] = make_float4(fmaxf(ha[4*q], 0.f), fmaxf(ha[4*q+1], 0.f),
                            fmaxf(ha[4*q+2], 0.f), fmaxf(ha[4*q+3], 0.f));
        pb[q] = make_float4(fmaxf(hb[4*q], 0.f), fmaxf(hb[4*q+1], 0.f),
                            fmaxf(hb[4*q+2], 0.f), fmaxf(hb[4*q+3], 0.f));
    }
}

// ---- GCN aggregate in h-space: gbuf = dinv2*h + sum wedge*h[src] --------
// Padded rows (multiple of 4): no scalar remainder. 2 nodes/thread,
// 4-edge batches, XCD-swizzled 1D grid.

#define AGG_GATHER4(J, ACC)                                                    \
    {                                                                          \
        int i0 = col[J], i1 = col[J+1], i2 = col[J+2], i3 = col[J+3];          \
        float w0 = wedge[J], w1_ = wedge[J+1], w2_ = wedge[J+2], w3 = wedge[J+3];\
        float v0 = xg[(size_t)i0 * 32 + c];                                    \
        float v1 = xg[(size_t)i1 * 32 + c];                                    \
        float v2 = xg[(size_t)i2 * 32 + c];                                    \
        float v3 = xg[(size_t)i3 * 32 + c];                                    \
        ACC += w0 * v0 + w1_ * v1 + w2_ * v2 + w3 * v3;                        \
    }

__global__ __launch_bounds__(256) void k_agg(const float* __restrict__ hbuf,
                                             const int* __restrict__ rowptr,
                                             const int* __restrict__ col,
                                             const float* __restrict__ wedge,
                                             const float* __restrict__ dinv2,
                                             float* __restrict__ gbuf) {
    // 24000 blocks: 8 xcd-slots x 24 graphs x 125 node-chunks of 16
    int bid = blockIdx.x;
    int xcd = bid & 7;
    int q   = bid >> 3;
    int g   = (q / 125) * 8 + xcd;
    int nch = q % 125;
    int c   = threadIdx.x & 31;
    int nl  = threadIdx.x >> 5;
    int n0  = nch * 16 + nl;
    int n1  = n0 + 8;
    const float* xg = hbuf + (size_t)g * NN * COUT;

    float accA = dinv2[n0] * xg[(size_t)n0 * 32 + c];
    float accB = dinv2[n1] * xg[(size_t)n1 * 32 + c];
    int jA = rowptr[n0], eA = rowptr[n0 + 1];
    int jB = rowptr[n1], eB = rowptr[n1 + 1];

    while (jA < eA && jB < eB) {
        AGG_GATHER4(jA, accA)
        AGG_GATHER4(jB, accB)
        jA += 4; jB += 4;
    }
    while (jA < eA) { AGG_GATHER4(jA, accA) jA += 4; }
    while (jB < eB) { AGG_GATHER4(jB, accB) jB += 4; }

    gbuf[((size_t)g * NN + n0) * 32 + c] = accA;
    gbuf[((size_t)g * NN + n1) * 32 + c] = accB;
}

// ---- conv2 with composed weights: out = b2 + sum_k (gbuf[tt] @ w2c[k] + bias2[k])

__global__ __launch_bounds__(256) void k_conv2(const float* __restrict__ gbuf,
                                               const float* __restrict__ w2c,
                                               const float* __restrict__ bias2,
                                               const float* __restrict__ b2,
                                               float* __restrict__ out) {
    int n = blockIdx.x * 256 + threadIdx.x;
    if (n >= NN) return;
    int t = blockIdx.y, b = blockIdx.z;

    float o[COUT];
#pragma unroll
    for (int c = 0; c < COUT; c++) o[c] = b2[c];

    for (int k = 0; k < 3; k++) {
        int tt = t + k - 1;
        if (tt < 0 || tt >= TT) continue;
        const float4* gp = (const float4*)(gbuf + (((size_t)(b * TT + tt)) * NN + n) * CIN);
        const float* wp = w2c + k * CIN * COUT;
        const float* bp = bias2 + k * COUT;
        float gv[CIN];
#pragma unroll
        for (int qq = 0; qq < 8; qq++) {
            float4 v = gp[qq];
            gv[4*qq] = v.x; gv[4*qq+1] = v.y; gv[4*qq+2] = v.z; gv[4*qq+3] = v.w;
        }
#pragma unroll
        for (int c = 0; c < COUT; c++) o[c] += bp[c];
#pragma unroll
        for (int cm = 0; cm < CIN; cm++) {
#pragma unroll
            for (int c = 0; c < COUT; c++) o[c] += gv[cm] * wp[cm * COUT + c];
        }
    }

#pragma unroll
    for (int c = 0; c < COUT; c++)
        out[(((size_t)b * COUT + c) * TT + t) * NN + n] = o[c];
}

// ---- launch -------------------------------------------------------------

extern "C" void kernel_launch(void* const* d_in, const int* in_sizes, int n_in,
                              void* d_out, int out_size, void* d_ws, size_t ws_size,
                              hipStream_t stream) {
    const float* x     = (const float*)d_in[0];
    const int*   ei    = (const int*)d_in[1];
    const float* w1    = (const float*)d_in[2];
    const float* b1    = (const float*)d_in[3];
    const float* gcn_w = (const float*)d_in[4];
    const float* gcn_b = (const float*)d_in[5];
    const float* w2    = (const float*)d_in[6];
    const float* b2    = (const float*)d_in[7];
    float* out = (float*)d_out;

    const size_t XWB = (size_t)BT * NN * COUT * sizeof(float);  // 49.152 MB
    char* w = (char*)d_ws;
    float* hbuf   = (float*)w;  w += XWB;
    float* gbuf   = (float*)w;  w += XWB;
    int*   rowptr = (int*)w;    w += 8192;
    float* dinv2  = (float*)w;  w += 8192;
    int*   col    = (int*)w;    w += PADCOL * sizeof(int);
    float* wedge  = (float*)w;  w += PADCOL * sizeof(float);
    float* w1t    = (float*)w;  w += 3072 * sizeof(float);
    float* w2c    = (float*)w;  w += 3072 * sizeof(float);
    float* bias2  = (float*)w;  w += 96 * sizeof(float);

    k_build<<<dim3(1), dim3(1024), 0, stream>>>(ei, w1, gcn_w, gcn_b, w2,
                                                rowptr, dinv2, col, wedge,
                                                w1t, w2c, bias2);
    k_conv1<<<dim3(4, TT, BB), dim3(256), 0, stream>>>(x, w1t, b1, hbuf);
    k_agg  <<<dim3(24000), dim3(256), 0, stream>>>(hbuf, rowptr, col, wedge, dinv2, gbuf);
    k_conv2<<<dim3(8, TT, BB), dim3(256), 0, stream>>>(gbuf, w2c, bias2, b2, out);
}

// Round 4
// 310.183 us; speedup vs baseline: 1.1195x; 1.1195x over previous
//
#include <hip/hip_runtime.h>

#define BB 4
#define CIN 32
#define COUT 32
#define TT 48
#define NN 2000
#define EE 16000
#define BT (BB*TT)
#define PADCOL 24576   // padded CSR capacity (16000 + 2000*3 = 22000 max)

// ---- fused build: CSR (padded rows) + degree terms + weight prep --------
// Single block, 1024 threads. All weight math goes through LDS staging:
// the R2 version read w2 with stride-384B gathers 32x per output at
// single-CU L1 bandwidth (~40us). Now: one strided pass into LDS
// (transposed, so compose reads are consecutive-bank), then compose.

__global__ __launch_bounds__(1024) void k_build(
        const int* __restrict__ ei,
        const float* __restrict__ w1, const float* __restrict__ gw,
        const float* __restrict__ gb, const float* __restrict__ w2,
        int* __restrict__ rowptr, float* __restrict__ dinv2,
        int* __restrict__ col, float* __restrict__ wedge,
        float* __restrict__ w1t, float* __restrict__ w2c,
        float* __restrict__ bias2) {
    __shared__ int   cnt[2048];
    __shared__ int   buf[2048];
    __shared__ float sdinv[2048];
    __shared__ float sw2t[3072];   // [k][co][c] transposed w2
    __shared__ float sgw[1024];
    int t = threadIdx.x;

    // 0. stage weights; write w1t (transpose) directly while we're at it
    for (int i = t; i < 3072; i += 1024) {
        int c = i & 31, r = i >> 5;
        int co = r & 31, k = r >> 5;           // i = (k*32+co)*32 + c
        float v2 = w2[c * 96 + co * 3 + k];
        sw2t[i] = v2;
        w1t[i]  = w1[c * 96 + co * 3 + k];     // co plays the role of ci
    }
    sgw[t] = gw[t];
    cnt[t] = 0; cnt[t + 1024] = 0;
    __syncthreads();

    // 1. count in-degrees (LDS atomics)
    for (int e = t; e < EE; e += 1024) atomicAdd(&cnt[ei[EE + e]], 1);
    __syncthreads();

    // 2. inclusive scan over PADDED counts (each row padded to multiple of 4)
    for (int i = t; i < 2048; i += 1024)
        buf[i] = (i < NN) ? ((cnt[i] + 3) & ~3) : 0;
    __syncthreads();
    for (int s = 1; s < 2048; s <<= 1) {
        int i0 = t, i1 = t + 1024;
        int a0 = buf[i0] + ((i0 >= s) ? buf[i0 - s] : 0);
        int a1 = buf[i1] + ((i1 >= s) ? buf[i1 - s] : 0);
        __syncthreads();
        buf[i0] = a0; buf[i1] = a1;
        __syncthreads();
    }

    // 3. rowptr + degree terms (deg = 1 + in-degree)
    for (int i = t; i < 2048; i += 1024) {
        if (i < NN) {
            rowptr[i + 1] = buf[i];
            float deg = (float)(cnt[i] + 1);
            sdinv[i] = rsqrtf(deg);
            dinv2[i] = 1.0f / deg;
        }
    }
    if (t == 0) rowptr[0] = 0;
    __syncthreads();

    // 4. zero padded col/wedge; repoint cnt[] to padded row starts
    int P = buf[NN - 1];
    for (int i = t; i < P; i += 1024) { col[i] = 0; wedge[i] = 0.f; }
    for (int i = t; i < NN; i += 1024)
        cnt[i] = buf[i] - ((cnt[i] + 3) & ~3);
    __syncthreads();

    // 5. fill real edges (scattered stores, L2-resident region)
    for (int e = t; e < EE; e += 1024) {
        int s = ei[e], d = ei[EE + e];
        int pos = atomicAdd(&cnt[d], 1);
        col[pos]   = s;
        wedge[pos] = sdinv[s] * sdinv[d];
    }

    // 6. compose w2c[k][cm][c] = sum_co gw[cm][co] * w2t[k][co][c]  (all LDS)
    for (int i = t; i < 3072; i += 1024) {
        int c = i & 31, r = i >> 5;
        int cm = r & 31, k = r >> 5;
        float acc = 0.f;
#pragma unroll
        for (int co = 0; co < 32; co++)
            acc += sgw[cm * 32 + co] * sw2t[(k * 32 + co) * 32 + c];
        w2c[i] = acc;
    }
    for (int i = t; i < 96; i += 1024) {
        int k = i >> 5, c = i & 31;
        float acc = 0.f;
#pragma unroll
        for (int co = 0; co < 32; co++)
            acc += gb[co] * sw2t[(k * 32 + co) * 32 + c];
        bias2[i] = acc;
    }
}

// ---- conv1: temporal conv + relu -> h [BT, N, 32] (c fastest) -----------

__global__ __launch_bounds__(256) void k_conv1(const float* __restrict__ x,
                                               const float* __restrict__ w1t,
                                               const float* __restrict__ b1,
                                               float* __restrict__ hbuf) {
    int idx = blockIdx.x * 256 + threadIdx.x;   // node-pair index
    int n0 = idx * 2;
    if (n0 >= NN) return;
    int t = blockIdx.y, b = blockIdx.z;

    float ha[COUT], hb[COUT];
#pragma unroll
    for (int c = 0; c < COUT; c++) { ha[c] = b1[c]; hb[c] = b1[c]; }

    for (int k = 0; k < 3; k++) {
        int tt = t + k - 1;
        if (tt < 0 || tt >= TT) continue;
        const float* xb = x + (((size_t)b * CIN) * TT + tt) * NN + n0;
        const float* wp = w1t + k * CIN * COUT;
#pragma unroll
        for (int ci = 0; ci < CIN; ci++) {
            float2 xv = *(const float2*)(xb + (size_t)ci * TT * NN);
#pragma unroll
            for (int c = 0; c < COUT; c++) {
                float wv = wp[ci * COUT + c];
                ha[c] += xv.x * wv;
                hb[c] += xv.y * wv;
            }
        }
    }

    float4* pa = (float4*)(hbuf + (((size_t)(b * TT + t)) * NN + n0) * COUT);
    float4* pb = pa + 8;
#pragma unroll
    for (int q = 0; q < 8; q++) {
        pa[q] = make_float4(fmaxf(ha[4*q], 0.f), fmaxf(ha[4*q+1], 0.f),
                            fmaxf(ha[4*q+2], 0.f), fmaxf(ha[4*q+3], 0.f));
        pb[q] = make_float4(fmaxf(hb[4*q], 0.f), fmaxf(hb[4*q+1], 0.f),
                            fmaxf(hb[4*q+2], 0.f), fmaxf(hb[4*q+3], 0.f));
    }
}

// ---- GCN aggregate in h-space -------------------------------------------
// float2 channels: 16 lanes per node, half the gather instructions of R2.
// Padded rows (x4): no scalar remainder. 2 nodes/thread ILP, XCD swizzle.

#define AGG_G4(J, AX, AY)                                                      \
    {                                                                          \
        int i0 = col[J], i1 = col[J+1], i2 = col[J+2], i3 = col[J+3];          \
        float w0 = wedge[J], w1_ = wedge[J+1], w2_ = wedge[J+2], w3_ = wedge[J+3];\
        float2 v0 = *(const float2*)(xg + (size_t)i0 * 32 + c2);               \
        float2 v1 = *(const float2*)(xg + (size_t)i1 * 32 + c2);               \
        float2 v2 = *(const float2*)(xg + (size_t)i2 * 32 + c2);               \
        float2 v3 = *(const float2*)(xg + (size_t)i3 * 32 + c2);               \
        AX += w0 * v0.x + w1_ * v1.x + w2_ * v2.x + w3_ * v3.x;                \
        AY += w0 * v0.y + w1_ * v1.y + w2_ * v2.y + w3_ * v3.y;                \
    }

__global__ __launch_bounds__(256) void k_agg(const float* __restrict__ hbuf,
                                             const int* __restrict__ rowptr,
                                             const int* __restrict__ col,
                                             const float* __restrict__ wedge,
                                             const float* __restrict__ dinv2,
                                             float* __restrict__ gbuf) {
    // 12096 blocks: 8 xcd-slots x 24 graph-groups x 63 chunks of 32 nodes
    int bid = blockIdx.x;
    int xcd = bid & 7;
    int q   = bid >> 3;
    int g   = (q / 63) * 8 + xcd;
    int nch = q % 63;
    int c2  = (threadIdx.x & 15) * 2;
    int nl  = threadIdx.x >> 4;          // 0..15
    int n0  = nch * 32 + nl;             // always < 2000 (62*32+15 = 1999)
    int n1  = n0 + 16;
    bool hasB = (n1 < NN);
    const float* xg = hbuf + (size_t)g * NN * COUT;

    float2 sA = *(const float2*)(xg + (size_t)n0 * 32 + c2);
    float dA = dinv2[n0];
    float axA = dA * sA.x, ayA = dA * sA.y;
    float axB = 0.f, ayB = 0.f;
    int jA = rowptr[n0], eA = rowptr[n0 + 1];
    int jB = 0, eB = 0;
    if (hasB) {
        float2 sB = *(const float2*)(xg + (size_t)n1 * 32 + c2);
        float dB = dinv2[n1];
        axB = dB * sB.x; ayB = dB * sB.y;
        jB = rowptr[n1]; eB = rowptr[n1 + 1];
    }

    while (jA < eA && jB < eB) {
        AGG_G4(jA, axA, ayA)
        AGG_G4(jB, axB, ayB)
        jA += 4; jB += 4;
    }
    while (jA < eA) { AGG_G4(jA, axA, ayA) jA += 4; }
    while (jB < eB) { AGG_G4(jB, axB, ayB) jB += 4; }

    *(float2*)(gbuf + ((size_t)g * NN + n0) * 32 + c2) = make_float2(axA, ayA);
    if (hasB)
        *(float2*)(gbuf + ((size_t)g * NN + n1) * 32 + c2) = make_float2(axB, ayB);
}

// ---- conv2 with composed weights ----------------------------------------

__global__ __launch_bounds__(256) void k_conv2(const float* __restrict__ gbuf,
                                               const float* __restrict__ w2c,
                                               const float* __restrict__ bias2,
                                               const float* __restrict__ b2,
                                               float* __restrict__ out) {
    int n = blockIdx.x * 256 + threadIdx.x;
    if (n >= NN) return;
    int t = blockIdx.y, b = blockIdx.z;

    float o[COUT];
#pragma unroll
    for (int c = 0; c < COUT; c++) o[c] = b2[c];

    for (int k = 0; k < 3; k++) {
        int tt = t + k - 1;
        if (tt < 0 || tt >= TT) continue;
        const float4* gp = (const float4*)(gbuf + (((size_t)(b * TT + tt)) * NN + n) * CIN);
        const float* wp = w2c + k * CIN * COUT;
        const float* bp = bias2 + k * COUT;
        float gv[CIN];
#pragma unroll
        for (int qq = 0; qq < 8; qq++) {
            float4 v = gp[qq];
            gv[4*qq] = v.x; gv[4*qq+1] = v.y; gv[4*qq+2] = v.z; gv[4*qq+3] = v.w;
        }
#pragma unroll
        for (int c = 0; c < COUT; c++) o[c] += bp[c];
#pragma unroll
        for (int cm = 0; cm < CIN; cm++) {
#pragma unroll
            for (int c = 0; c < COUT; c++) o[c] += gv[cm] * wp[cm * COUT + c];
        }
    }

#pragma unroll
    for (int c = 0; c < COUT; c++)
        out[(((size_t)b * COUT + c) * TT + t) * NN + n] = o[c];
}

// ---- launch -------------------------------------------------------------

extern "C" void kernel_launch(void* const* d_in, const int* in_sizes, int n_in,
                              void* d_out, int out_size, void* d_ws, size_t ws_size,
                              hipStream_t stream) {
    const float* x     = (const float*)d_in[0];
    const int*   ei    = (const int*)d_in[1];
    const float* w1    = (const float*)d_in[2];
    const float* b1    = (const float*)d_in[3];
    const float* gcn_w = (const float*)d_in[4];
    const float* gcn_b = (const float*)d_in[5];
    const float* w2    = (const float*)d_in[6];
    const float* b2    = (const float*)d_in[7];
    float* out = (float*)d_out;

    const size_t XWB = (size_t)BT * NN * COUT * sizeof(float);  // 49.152 MB
    char* w = (char*)d_ws;
    float* hbuf   = (float*)w;  w += XWB;
    float* gbuf   = (float*)w;  w += XWB;
    int*   rowptr = (int*)w;    w += 8192;
    float* dinv2  = (float*)w;  w += 8192;
    int*   col    = (int*)w;    w += PADCOL * sizeof(int);
    float* wedge  = (float*)w;  w += PADCOL * sizeof(float);
    float* w1t    = (float*)w;  w += 3072 * sizeof(float);
    float* w2c    = (float*)w;  w += 3072 * sizeof(float);
    float* bias2  = (float*)w;  w += 96 * sizeof(float);

    k_build<<<dim3(1), dim3(1024), 0, stream>>>(ei, w1, gcn_w, gcn_b, w2,
                                                rowptr, dinv2, col, wedge,
                                                w1t, w2c, bias2);
    k_conv1<<<dim3(4, TT, BB), dim3(256), 0, stream>>>(x, w1t, b1, hbuf);
    k_agg  <<<dim3(12096), dim3(256), 0, stream>>>(hbuf, rowptr, col, wedge, dinv2, gbuf);
    k_conv2<<<dim3(8, TT, BB), dim3(256), 0, stream>>>(gbuf, w2c, bias2, b2, out);
}

// Round 5
// 269.108 us; speedup vs baseline: 1.2904x; 1.1526x over previous
//
#include <hip/hip_runtime.h>

#define BB 4
#define CIN 32
#define COUT 32
#define TT 48
#define NN 2000
#define EE 16000
#define BT (BB*TT)
#define PADCOL 24576   // padded CSR capacity (16000 + 2000*3 = 22000 max)
#define NGB 24         // graph bundles of 8: 192 = 24*8

// ---- fused build: CSR (padded rows) + degree terms + weight prep --------

__global__ __launch_bounds__(1024) void k_build(
        const int* __restrict__ ei,
        const float* __restrict__ w1, const float* __restrict__ gw,
        const float* __restrict__ gb, const float* __restrict__ w2,
        int* __restrict__ rowptr, float* __restrict__ dinv2,
        int* __restrict__ col, float* __restrict__ wedge,
        float* __restrict__ w1t, float* __restrict__ w2c,
        float* __restrict__ bias2) {
    __shared__ int   cnt[2048];
    __shared__ int   buf[2048];
    __shared__ float sdinv[2048];
    __shared__ float sw2t[3072];   // [k][co][c] transposed w2
    __shared__ float sgw[1024];
    int t = threadIdx.x;

    // 0. stage weights; write w1t (transpose) directly
    for (int i = t; i < 3072; i += 1024) {
        int c = i & 31, r = i >> 5;
        int co = r & 31, k = r >> 5;           // i = (k*32+co)*32 + c
        sw2t[i] = w2[c * 96 + co * 3 + k];
        w1t[i]  = w1[c * 96 + co * 3 + k];
    }
    sgw[t] = gw[t];
    cnt[t] = 0; cnt[t + 1024] = 0;
    __syncthreads();

    // 1. count in-degrees (LDS atomics)
    for (int e = t; e < EE; e += 1024) atomicAdd(&cnt[ei[EE + e]], 1);
    __syncthreads();

    // 2. inclusive scan over PADDED counts (rows padded to multiple of 4)
    for (int i = t; i < 2048; i += 1024)
        buf[i] = (i < NN) ? ((cnt[i] + 3) & ~3) : 0;
    __syncthreads();
    for (int s = 1; s < 2048; s <<= 1) {
        int i0 = t, i1 = t + 1024;
        int a0 = buf[i0] + ((i0 >= s) ? buf[i0 - s] : 0);
        int a1 = buf[i1] + ((i1 >= s) ? buf[i1 - s] : 0);
        __syncthreads();
        buf[i0] = a0; buf[i1] = a1;
        __syncthreads();
    }

    // 3. rowptr + degree terms (deg = 1 + in-degree)
    for (int i = t; i < 2048; i += 1024) {
        if (i < NN) {
            rowptr[i + 1] = buf[i];
            float deg = (float)(cnt[i] + 1);
            sdinv[i] = rsqrtf(deg);
            dinv2[i] = 1.0f / deg;
        }
    }
    if (t == 0) rowptr[0] = 0;
    __syncthreads();

    // 4. zero padded col/wedge; repoint cnt[] to padded row starts
    int P = buf[NN - 1];
    for (int i = t; i < P; i += 1024) { col[i] = 0; wedge[i] = 0.f; }
    for (int i = t; i < NN; i += 1024)
        cnt[i] = buf[i] - ((cnt[i] + 3) & ~3);
    __syncthreads();

    // 5. fill real edges
    for (int e = t; e < EE; e += 1024) {
        int s = ei[e], d = ei[EE + e];
        int pos = atomicAdd(&cnt[d], 1);
        col[pos]   = s;
        wedge[pos] = sdinv[s] * sdinv[d];
    }

    // 6. compose w2c[k][cm][c] = sum_co gw[cm][co] * w2t[k][co][c]  (all LDS)
    for (int i = t; i < 3072; i += 1024) {
        int c = i & 31, r = i >> 5;
        int cm = r & 31, k = r >> 5;
        float acc = 0.f;
#pragma unroll
        for (int co = 0; co < 32; co++)
            acc += sgw[cm * 32 + co] * sw2t[(k * 32 + co) * 32 + c];
        w2c[i] = acc;
    }
    for (int i = t; i < 96; i += 1024) {
        int k = i >> 5, c = i & 31;
        float acc = 0.f;
#pragma unroll
        for (int co = 0; co < 32; co++)
            acc += gb[co] * sw2t[(k * 32 + co) * 32 + c];
        bias2[i] = acc;
    }
}

// ---- conv1: temporal conv + relu -> hbuf BUNDLED [gb][n][gsub][c] -------

__global__ __launch_bounds__(256) void k_conv1(const float* __restrict__ x,
                                               const float* __restrict__ w1t,
                                               const float* __restrict__ b1,
                                               float* __restrict__ hbuf) {
    int idx = blockIdx.x * 256 + threadIdx.x;   // node-pair index
    int n0 = idx * 2;
    if (n0 >= NN) return;
    int t = blockIdx.y, b = blockIdx.z;
    int g = b * TT + t;
    int gb = g >> 3, gsub = g & 7;

    float ha[COUT], hb[COUT];
#pragma unroll
    for (int c = 0; c < COUT; c++) { ha[c] = b1[c]; hb[c] = b1[c]; }

    for (int k = 0; k < 3; k++) {
        int tt = t + k - 1;
        if (tt < 0 || tt >= TT) continue;
        const float* xb = x + (((size_t)b * CIN) * TT + tt) * NN + n0;
        const float* wp = w1t + k * CIN * COUT;
#pragma unroll
        for (int ci = 0; ci < CIN; ci++) {
            float2 xv = *(const float2*)(xb + (size_t)ci * TT * NN);
#pragma unroll
            for (int c = 0; c < COUT; c++) {
                float wv = wp[ci * COUT + c];
                ha[c] += xv.x * wv;
                hb[c] += xv.y * wv;
            }
        }
    }

    // bundled writes: 128 B chunk per node (fully-dirtied lines)
    float4* pa = (float4*)(hbuf + (((size_t)gb * NN + n0) * 8 + gsub) * 32);
    float4* pb = (float4*)(hbuf + (((size_t)gb * NN + n0 + 1) * 8 + gsub) * 32);
#pragma unroll
    for (int q = 0; q < 8; q++) {
        pa[q] = make_float4(fmaxf(ha[4*q], 0.f), fmaxf(ha[4*q+1], 0.f),
                            fmaxf(ha[4*q+2], 0.f), fmaxf(ha[4*q+3], 0.f));
        pb[q] = make_float4(fmaxf(hb[4*q], 0.f), fmaxf(hb[4*q+1], 0.f),
                            fmaxf(hb[4*q+2], 0.f), fmaxf(hb[4*q+3], 0.f));
    }
}

// ---- GCN aggregate, graph-bundled ---------------------------------------
// One wave per (gb, dst-node): 64 lanes = 8 gsub x 8 c-quads. Each edge
// gather = ONE fully-coalesced 1 KB float4 load. col/wedge read as
// broadcast int4/float4 per 4-edge batch. Uniform trip count (padded x4),
// no divergence. Output written in STANDARD [g][n][c] layout for conv2.

__global__ __launch_bounds__(256) void k_agg(const float* __restrict__ hbuf,
                                             const int* __restrict__ rowptr,
                                             const int* __restrict__ col,
                                             const float* __restrict__ wedge,
                                             const float* __restrict__ dinv2,
                                             float* __restrict__ gbuf) {
    // 12000 blocks: 8 xcd-slots x 3 bundle-rows x 500 node-quads
    int bid = blockIdx.x;
    int xcd = bid & 7;
    int q   = bid >> 3;              // 0..1499
    int gbr = q / 500;               // 0..2
    int nch = q % 500;
    int gb  = gbr * 8 + xcd;         // bundle pinned to one XCD slot
    int wid  = threadIdx.x >> 6;     // wave 0..3
    int lane = threadIdx.x & 63;
    int gsub = lane >> 3;            // 0..7
    int cq   = lane & 7;             // c = cq*4
    int n    = nch * 4 + wid;

    const float* xg = hbuf + (size_t)gb * NN * 256;   // bundle slice
    size_t loff = (size_t)gsub * 32 + cq * 4;

    float4 self = *(const float4*)(xg + (size_t)n * 256 + loff);
    float dv = dinv2[n];
    float4 acc = make_float4(dv * self.x, dv * self.y, dv * self.z, dv * self.w);

    int j  = rowptr[n];
    int je = rowptr[n + 1];
    for (; j < je; j += 4) {        // padded: je-j always multiple of 4
        int4   cc = *(const int4*)(col + j);
        float4 ww = *(const float4*)(wedge + j);
        float4 v0 = *(const float4*)(xg + (size_t)cc.x * 256 + loff);
        float4 v1 = *(const float4*)(xg + (size_t)cc.y * 256 + loff);
        float4 v2 = *(const float4*)(xg + (size_t)cc.z * 256 + loff);
        float4 v3 = *(const float4*)(xg + (size_t)cc.w * 256 + loff);
        acc.x += ww.x*v0.x + ww.y*v1.x + ww.z*v2.x + ww.w*v3.x;
        acc.y += ww.x*v0.y + ww.y*v1.y + ww.z*v2.y + ww.w*v3.y;
        acc.z += ww.x*v0.z + ww.y*v1.z + ww.z*v2.z + ww.w*v3.z;
        acc.w += ww.x*v0.w + ww.y*v1.w + ww.z*v2.w + ww.w*v3.w;
    }

    // standard layout out: g = gb*8 + gsub
    int g = gb * 8 + gsub;
    *(float4*)(gbuf + ((size_t)g * NN + n) * 32 + cq * 4) = acc;
}

// ---- conv2 with composed weights (reads standard [g][n][c]) -------------

__global__ __launch_bounds__(256) void k_conv2(const float* __restrict__ gbuf,
                                               const float* __restrict__ w2c,
                                               const float* __restrict__ bias2,
                                               const float* __restrict__ b2,
                                               float* __restrict__ out) {
    int n = blockIdx.x * 256 + threadIdx.x;
    if (n >= NN) return;
    int t = blockIdx.y, b = blockIdx.z;

    float o[COUT];
#pragma unroll
    for (int c = 0; c < COUT; c++) o[c] = b2[c];

    for (int k = 0; k < 3; k++) {
        int tt = t + k - 1;
        if (tt < 0 || tt >= TT) continue;
        const float4* gp = (const float4*)(gbuf + (((size_t)(b * TT + tt)) * NN + n) * CIN);
        const float* wp = w2c + k * CIN * COUT;
        const float* bp = bias2 + k * COUT;
        float gv[CIN];
#pragma unroll
        for (int qq = 0; qq < 8; qq++) {
            float4 v = gp[qq];
            gv[4*qq] = v.x; gv[4*qq+1] = v.y; gv[4*qq+2] = v.z; gv[4*qq+3] = v.w;
        }
#pragma unroll
        for (int c = 0; c < COUT; c++) o[c] += bp[c];
#pragma unroll
        for (int cm = 0; cm < CIN; cm++) {
#pragma unroll
            for (int c = 0; c < COUT; c++) o[c] += gv[cm] * wp[cm * COUT + c];
        }
    }

#pragma unroll
    for (int c = 0; c < COUT; c++)
        out[(((size_t)b * COUT + c) * TT + t) * NN + n] = o[c];
}

// ---- launch -------------------------------------------------------------

extern "C" void kernel_launch(void* const* d_in, const int* in_sizes, int n_in,
                              void* d_out, int out_size, void* d_ws, size_t ws_size,
                              hipStream_t stream) {
    const float* x     = (const float*)d_in[0];
    const int*   ei    = (const int*)d_in[1];
    const float* w1    = (const float*)d_in[2];
    const float* b1    = (const float*)d_in[3];
    const float* gcn_w = (const float*)d_in[4];
    const float* gcn_b = (const float*)d_in[5];
    const float* w2    = (const float*)d_in[6];
    const float* b2    = (const float*)d_in[7];
    float* out = (float*)d_out;

    const size_t XWB = (size_t)BT * NN * COUT * sizeof(float);  // 49.152 MB
    char* w = (char*)d_ws;
    float* hbuf   = (float*)w;  w += XWB;   // bundled [gb][n][gsub][c]
    float* gbuf   = (float*)w;  w += XWB;   // standard [g][n][c]
    int*   rowptr = (int*)w;    w += 8192;
    float* dinv2  = (float*)w;  w += 8192;
    int*   col    = (int*)w;    w += PADCOL * sizeof(int);
    float* wedge  = (float*)w;  w += PADCOL * sizeof(float);
    float* w1t    = (float*)w;  w += 3072 * sizeof(float);
    float* w2c    = (float*)w;  w += 3072 * sizeof(float);
    float* bias2  = (float*)w;  w += 96 * sizeof(float);

    k_build<<<dim3(1), dim3(1024), 0, stream>>>(ei, w1, gcn_w, gcn_b, w2,
                                                rowptr, dinv2, col, wedge,
                                                w1t, w2c, bias2);
    k_conv1<<<dim3(4, TT, BB), dim3(256), 0, stream>>>(x, w1t, b1, hbuf);
    k_agg  <<<dim3(12000), dim3(256), 0, stream>>>(hbuf, rowptr, col, wedge, dinv2, gbuf);
    k_conv2<<<dim3(8, TT, BB), dim3(256), 0, stream>>>(gbuf, w2c, bias2, b2, out);
}

// Round 6
// 257.402 us; speedup vs baseline: 1.3491x; 1.0455x over previous
//
#include <hip/hip_runtime.h>

#define BB 4
#define CIN 32
#define COUT 32
#define TT 48
#define NN 2000
#define EE 16000
#define BT (BB*TT)
#define PADCOL 24576   // padded CSR capacity (16000 + 2000*3 = 22000 max)

// ---- build: counts, scan, rowptr, degree terms, weight prep -------------
// Single block. Edge fill moved OUT (it was single-CU scattered stores).

__global__ __launch_bounds__(1024) void k_build(
        const int* __restrict__ ei,
        const float* __restrict__ w1, const float* __restrict__ gw,
        const float* __restrict__ gb, const float* __restrict__ w2,
        int* __restrict__ rowptr, float* __restrict__ dinv2,
        float* __restrict__ dinvg, int* __restrict__ fillptr,
        int* __restrict__ col, float* __restrict__ wedge,
        float* __restrict__ w1t, float* __restrict__ w2c,
        float* __restrict__ bias2) {
    __shared__ int   cnt[2048];
    __shared__ int   buf[2048];
    __shared__ float sw2t[3072];   // [k][co][c] transposed w2
    __shared__ float sgw[1024];
    int t = threadIdx.x;

    // 0. stage weights; write w1t (transpose) directly
    for (int i = t; i < 3072; i += 1024) {
        int c = i & 31, r = i >> 5;
        int co = r & 31, k = r >> 5;           // i = (k*32+co)*32 + c
        sw2t[i] = w2[c * 96 + co * 3 + k];
        w1t[i]  = w1[c * 96 + co * 3 + k];
    }
    sgw[t] = gw[t];
    cnt[t] = 0; cnt[t + 1024] = 0;
    __syncthreads();

    // 1. count in-degrees (LDS atomics)
    for (int e = t; e < EE; e += 1024) atomicAdd(&cnt[ei[EE + e]], 1);
    __syncthreads();

    // 2. inclusive scan over PADDED counts (rows padded to multiple of 4)
    for (int i = t; i < 2048; i += 1024)
        buf[i] = (i < NN) ? ((cnt[i] + 3) & ~3) : 0;
    __syncthreads();
    for (int s = 1; s < 2048; s <<= 1) {
        int i0 = t, i1 = t + 1024;
        int a0 = buf[i0] + ((i0 >= s) ? buf[i0 - s] : 0);
        int a1 = buf[i1] + ((i1 >= s) ? buf[i1 - s] : 0);
        __syncthreads();
        buf[i0] = a0; buf[i1] = a1;
        __syncthreads();
    }

    // 3. rowptr + degree terms + global fill pointers
    for (int i = t; i < 2048; i += 1024) {
        if (i < NN) {
            rowptr[i + 1] = buf[i];
            float deg = (float)(cnt[i] + 1);
            dinvg[i] = rsqrtf(deg);
            dinv2[i] = 1.0f / deg;
            fillptr[i] = buf[i] - ((cnt[i] + 3) & ~3);  // padded row start
        }
    }
    if (t == 0) rowptr[0] = 0;

    // 4. zero padded col/wedge (P <= PADCOL)
    int P = buf[NN - 1];
    __syncthreads();
    for (int i = t; i < P; i += 1024) { col[i] = 0; wedge[i] = 0.f; }

    // 5. compose w2c[k][cm][c] = sum_co gw[cm][co] * w2t[k][co][c]  (all LDS)
    for (int i = t; i < 3072; i += 1024) {
        int c = i & 31, r = i >> 5;
        int cm = r & 31, k = r >> 5;
        float acc = 0.f;
#pragma unroll
        for (int co = 0; co < 32; co++)
            acc += sgw[cm * 32 + co] * sw2t[(k * 32 + co) * 32 + c];
        w2c[i] = acc;
    }
    for (int i = t; i < 96; i += 1024) {
        int k = i >> 5, c = i & 31;
        float acc = 0.f;
#pragma unroll
        for (int co = 0; co < 32; co++)
            acc += gb[co] * sw2t[(k * 32 + co) * 32 + c];
        bias2[i] = acc;
    }
}

// ---- edge fill: parallel across CUs (device-scope atomics) --------------

__global__ void k_fill(const int* __restrict__ ei, int* __restrict__ fillptr,
                       const float* __restrict__ dinvg,
                       int* __restrict__ col, float* __restrict__ wedge) {
    int e = blockIdx.x * blockDim.x + threadIdx.x;
    if (e < EE) {
        int s = ei[e], d = ei[EE + e];
        int pos = atomicAdd(fillptr + d, 1);
        col[pos]   = s;
        wedge[pos] = dinvg[s] * dinvg[d];
    }
}

// ---- conv1: temporal conv + relu -> hbuf BUNDLED [gb][n][gsub][c] -------
// 1 node/thread: 1536 blocks -> 24 waves/CU ceiling (R4 had 768 -> 12,
// occupancy-starved at 23.7%).

__global__ __launch_bounds__(256) void k_conv1(const float* __restrict__ x,
                                               const float* __restrict__ w1t,
                                               const float* __restrict__ b1,
                                               float* __restrict__ hbuf) {
    int n = blockIdx.x * 256 + threadIdx.x;
    if (n >= NN) return;
    int t = blockIdx.y, b = blockIdx.z;
    int g = b * TT + t;
    int gb = g >> 3, gsub = g & 7;

    float ha[COUT];
#pragma unroll
    for (int c = 0; c < COUT; c++) ha[c] = b1[c];

    for (int k = 0; k < 3; k++) {
        int tt = t + k - 1;
        if (tt < 0 || tt >= TT) continue;
        const float* xb = x + (((size_t)b * CIN) * TT + tt) * NN + n;
        const float* wp = w1t + k * CIN * COUT;
#pragma unroll
        for (int ci = 0; ci < CIN; ci++) {
            float xv = xb[(size_t)ci * TT * NN];
#pragma unroll
            for (int c = 0; c < COUT; c++) ha[c] += xv * wp[ci * COUT + c];
        }
    }

    float4* pa = (float4*)(hbuf + (((size_t)gb * NN + n) * 8 + gsub) * 32);
#pragma unroll
    for (int q = 0; q < 8; q++)
        pa[q] = make_float4(fmaxf(ha[4*q], 0.f), fmaxf(ha[4*q+1], 0.f),
                            fmaxf(ha[4*q+2], 0.f), fmaxf(ha[4*q+3], 0.f));
}

// ---- GCN aggregate, graph-bundled (unchanged from R4: out of top-5) -----

__global__ __launch_bounds__(256) void k_agg(const float* __restrict__ hbuf,
                                             const int* __restrict__ rowptr,
                                             const int* __restrict__ col,
                                             const float* __restrict__ wedge,
                                             const float* __restrict__ dinv2,
                                             float* __restrict__ gbuf) {
    // 12000 blocks: 8 xcd-slots x 3 bundle-rows x 500 node-quads
    int bid = blockIdx.x;
    int xcd = bid & 7;
    int q   = bid >> 3;
    int gbr = q / 500;
    int nch = q % 500;
    int gb  = gbr * 8 + xcd;
    int wid  = threadIdx.x >> 6;
    int lane = threadIdx.x & 63;
    int gsub = lane >> 3;
    int cq   = lane & 7;
    int n    = nch * 4 + wid;

    const float* xg = hbuf + (size_t)gb * NN * 256;
    size_t loff = (size_t)gsub * 32 + cq * 4;

    float4 self = *(const float4*)(xg + (size_t)n * 256 + loff);
    float dv = dinv2[n];
    float4 acc = make_float4(dv * self.x, dv * self.y, dv * self.z, dv * self.w);

    int j  = rowptr[n];
    int je = rowptr[n + 1];
    for (; j < je; j += 4) {
        int4   cc = *(const int4*)(col + j);
        float4 ww = *(const float4*)(wedge + j);
        float4 v0 = *(const float4*)(xg + (size_t)cc.x * 256 + loff);
        float4 v1 = *(const float4*)(xg + (size_t)cc.y * 256 + loff);
        float4 v2 = *(const float4*)(xg + (size_t)cc.z * 256 + loff);
        float4 v3 = *(const float4*)(xg + (size_t)cc.w * 256 + loff);
        acc.x += ww.x*v0.x + ww.y*v1.x + ww.z*v2.x + ww.w*v3.x;
        acc.y += ww.x*v0.y + ww.y*v1.y + ww.z*v2.y + ww.w*v3.y;
        acc.z += ww.x*v0.z + ww.y*v1.z + ww.z*v2.z + ww.w*v3.z;
        acc.w += ww.x*v0.w + ww.y*v1.w + ww.z*v2.w + ww.w*v3.w;
    }

    int g = gb * 8 + gsub;
    *(float4*)(gbuf + ((size_t)g * NN + n) * 32 + cq * 4) = acc;
}

// ---- conv2 with composed weights (reads standard [g][n][c]) -------------

__global__ __launch_bounds__(256) void k_conv2(const float* __restrict__ gbuf,
                                               const float* __restrict__ w2c,
                                               const float* __restrict__ bias2,
                                               const float* __restrict__ b2,
                                               float* __restrict__ out) {
    int n = blockIdx.x * 256 + threadIdx.x;
    if (n >= NN) return;
    int t = blockIdx.y, b = blockIdx.z;

    float o[COUT];
#pragma unroll
    for (int c = 0; c < COUT; c++) o[c] = b2[c];

    for (int k = 0; k < 3; k++) {
        int tt = t + k - 1;
        if (tt < 0 || tt >= TT) continue;
        const float4* gp = (const float4*)(gbuf + (((size_t)(b * TT + tt)) * NN + n) * CIN);
        const float* wp = w2c + k * CIN * COUT;
        const float* bp = bias2 + k * COUT;
        float gv[CIN];
#pragma unroll
        for (int qq = 0; qq < 8; qq++) {
            float4 v = gp[qq];
            gv[4*qq] = v.x; gv[4*qq+1] = v.y; gv[4*qq+2] = v.z; gv[4*qq+3] = v.w;
        }
#pragma unroll
        for (int c = 0; c < COUT; c++) o[c] += bp[c];
#pragma unroll
        for (int cm = 0; cm < CIN; cm++) {
#pragma unroll
            for (int c = 0; c < COUT; c++) o[c] += gv[cm] * wp[cm * COUT + c];
        }
    }

#pragma unroll
    for (int c = 0; c < COUT; c++)
        out[(((size_t)b * COUT + c) * TT + t) * NN + n] = o[c];
}

// ---- launch -------------------------------------------------------------

extern "C" void kernel_launch(void* const* d_in, const int* in_sizes, int n_in,
                              void* d_out, int out_size, void* d_ws, size_t ws_size,
                              hipStream_t stream) {
    const float* x     = (const float*)d_in[0];
    const int*   ei    = (const int*)d_in[1];
    const float* w1    = (const float*)d_in[2];
    const float* b1    = (const float*)d_in[3];
    const float* gcn_w = (const float*)d_in[4];
    const float* gcn_b = (const float*)d_in[5];
    const float* w2    = (const float*)d_in[6];
    const float* b2    = (const float*)d_in[7];
    float* out = (float*)d_out;

    const size_t XWB = (size_t)BT * NN * COUT * sizeof(float);  // 49.152 MB
    char* w = (char*)d_ws;
    float* hbuf    = (float*)w;  w += XWB;   // bundled [gb][n][gsub][c]
    float* gbuf    = (float*)w;  w += XWB;   // standard [g][n][c]
    int*   rowptr  = (int*)w;    w += 8192;
    float* dinv2   = (float*)w;  w += 8192;
    float* dinvg   = (float*)w;  w += 8192;
    int*   fillptr = (int*)w;    w += 8192;
    int*   col     = (int*)w;    w += PADCOL * sizeof(int);
    float* wedge   = (float*)w;  w += PADCOL * sizeof(float);
    float* w1t     = (float*)w;  w += 3072 * sizeof(float);
    float* w2c     = (float*)w;  w += 3072 * sizeof(float);
    float* bias2   = (float*)w;  w += 96 * sizeof(float);

    k_build<<<dim3(1), dim3(1024), 0, stream>>>(ei, w1, gcn_w, gcn_b, w2,
                                                rowptr, dinv2, dinvg, fillptr,
                                                col, wedge, w1t, w2c, bias2);
    k_fill <<<dim3((EE + 255) / 256), dim3(256), 0, stream>>>(ei, fillptr, dinvg, col, wedge);
    k_conv1<<<dim3(8, TT, BB), dim3(256), 0, stream>>>(x, w1t, b1, hbuf);
    k_agg  <<<dim3(12000), dim3(256), 0, stream>>>(hbuf, rowptr, col, wedge, dinv2, gbuf);
    k_conv2<<<dim3(8, TT, BB), dim3(256), 0, stream>>>(gbuf, w2c, bias2, b2, out);
}